// Round 1
// baseline (1958.376 us; speedup 1.0000x reference)
//
#include <hip/hip_runtime.h>

// GCN link predictor, fp32.
// N=100000 nodes, E=1e6 edges, P=1e5 pairs, IN=128, H=64.
// ws layout (floats): norm_src[N] | norm_dst[N] | deg_out(int)[N] | deg_in(int)[N]
//                     | hw[N*64] | agg[N*64]   => 132*N floats = 52.8 MB

#define NN 100000
#define NE 1000000
#define NP 100000

__global__ void deg_kernel(const int* __restrict__ src, const int* __restrict__ dst,
                           int* __restrict__ deg_out, int* __restrict__ deg_in, int E) {
    int tid = blockIdx.x * blockDim.x + threadIdx.x;
    int stride = gridDim.x * blockDim.x;
    for (int e = tid; e < E; e += stride) {
        atomicAdd(&deg_out[src[e]], 1);
        atomicAdd(&deg_in[dst[e]], 1);
    }
}

__global__ void norm_kernel(const int* __restrict__ deg_out, const int* __restrict__ deg_in,
                            float* __restrict__ norm_src, float* __restrict__ norm_dst, int n) {
    int i = blockIdx.x * blockDim.x + threadIdx.x;
    if (i < n) {
        norm_src[i] = rsqrtf(fmaxf((float)deg_out[i], 1.0f));
        norm_dst[i] = rsqrtf(fmaxf((float)deg_in[i], 1.0f));
    }
}

// One wave per row: out[row][j] = norm_src[row] * sum_k t[row][k] * W[k][j]
// PREV:  t = relu(in*norm_dst + bias)  (K=64)   else t = in (K=128, layer 0)
template <int K, bool PREV>
__global__ void gemm_kernel(const float* __restrict__ in, const float* __restrict__ W,
                            const float* __restrict__ bias,
                            const float* __restrict__ norm_src, const float* __restrict__ norm_dst,
                            float* __restrict__ out, int n) {
    __shared__ float Wl[K * 64];
    for (int i = threadIdx.x; i < K * 64; i += blockDim.x) Wl[i] = W[i];
    __syncthreads();

    const int lane = threadIdx.x & 63;
    const int wid = threadIdx.x >> 6;
    const int wavesPerBlk = blockDim.x >> 6;
    const int gw = blockIdx.x * wavesPerBlk + wid;
    const int nw = gridDim.x * wavesPerBlk;

    float blane = 0.f;
    if constexpr (PREV) blane = bias[lane];

    for (int row = gw; row < n; row += nw) {
        float rv0, rv1 = 0.f;
        if constexpr (PREV) {
            float nd = norm_dst[row];
            rv0 = fmaxf(in[row * K + lane] * nd + blane, 0.f);
        } else {
            rv0 = in[row * K + lane];
            if (K == 128) rv1 = in[row * K + 64 + lane];
        }
        float acc = 0.f;
#pragma unroll
        for (int k = 0; k < 64; ++k)
            acc = fmaf(__shfl(rv0, k, 64), Wl[k * 64 + lane], acc);
        if constexpr (K == 128) {
#pragma unroll
            for (int k = 0; k < 64; ++k)
                acc = fmaf(__shfl(rv1, k, 64), Wl[64 * 64 + k * 64 + lane], acc);
        }
        out[row * 64 + lane] = acc * norm_src[row];
    }
}

// One wave per edge: agg[dst[e]][lane] += hw[src[e]][lane] * ew[e]
__global__ void scatter_kernel(const float* __restrict__ hw, const float* __restrict__ ew,
                               const int* __restrict__ src, const int* __restrict__ dst,
                               float* __restrict__ agg, int E) {
    const int lane = threadIdx.x & 63;
    const int gw = (blockIdx.x * blockDim.x + threadIdx.x) >> 6;
    const int nw = (gridDim.x * blockDim.x) >> 6;
    for (int e = gw; e < E; e += nw) {
        int s = src[e], d = dst[e];
        float w = ew[e];
        atomicAdd(&agg[d * 64 + lane], hw[s * 64 + lane] * w);
    }
}

// One wave per pair. h[i] = agg[i]*norm_dst[i] + b2 (final layer, no relu), computed on the fly.
__global__ void mlp_kernel(const float* __restrict__ agg, const float* __restrict__ norm_dst,
                           const float* __restrict__ b2,
                           const float* __restrict__ P0, const float* __restrict__ pb0,
                           const float* __restrict__ P1, const float* __restrict__ pb1,
                           const float* __restrict__ P2, const float* __restrict__ pb2,
                           const int* __restrict__ pos_src, const int* __restrict__ pos_dst,
                           const int* __restrict__ neg_src, const int* __restrict__ neg_dst,
                           float* __restrict__ out, int P) {
    __shared__ float P0l[64 * 64], P1l[64 * 64];
    __shared__ float P2l[64], pb0l[64], pb1l[64], b2l[64];
    for (int i = threadIdx.x; i < 64 * 64; i += blockDim.x) {
        P0l[i] = P0[i];
        P1l[i] = P1[i];
    }
    if (threadIdx.x < 64) {
        P2l[threadIdx.x] = P2[threadIdx.x];
        pb0l[threadIdx.x] = pb0[threadIdx.x];
        pb1l[threadIdx.x] = pb1[threadIdx.x];
        b2l[threadIdx.x] = b2[threadIdx.x];
    }
    __syncthreads();

    const int lane = threadIdx.x & 63;
    const int gw = (blockIdx.x * blockDim.x + threadIdx.x) >> 6;
    const int nw = (gridDim.x * blockDim.x) >> 6;
    const float p2v = P2l[lane];
    const float pb2v = pb2[0];

    for (int p = gw; p < 2 * P; p += nw) {
        int a, b;
        if (p < P) { a = pos_src[p]; b = pos_dst[p]; }
        else       { a = neg_src[p - P]; b = neg_dst[p - P]; }
        float ha = agg[a * 64 + lane] * norm_dst[a] + b2l[lane];
        float hb = agg[b * 64 + lane] * norm_dst[b] + b2l[lane];
        float z = ha * hb;

        float acc = pb0l[lane];
#pragma unroll
        for (int k = 0; k < 64; ++k)
            acc = fmaf(__shfl(z, k, 64), P0l[k * 64 + lane], acc);
        float z1 = fmaxf(acc, 0.f);

        acc = pb1l[lane];
#pragma unroll
        for (int k = 0; k < 64; ++k)
            acc = fmaf(__shfl(z1, k, 64), P1l[k * 64 + lane], acc);
        float z2 = fmaxf(acc, 0.f);

        float t = z2 * p2v;
#pragma unroll
        for (int off = 32; off > 0; off >>= 1) t += __shfl_down(t, off, 64);
        if (lane == 0) out[p] = t + pb2v;
    }
}

extern "C" void kernel_launch(void* const* d_in, const int* in_sizes, int n_in,
                              void* d_out, int out_size, void* d_ws, size_t ws_size,
                              hipStream_t stream) {
    const float* x       = (const float*)d_in[0];
    const float* ew      = (const float*)d_in[1];   // (3, E)
    const int* src       = (const int*)d_in[2];
    const int* dst       = (const int*)d_in[3];
    const int* pos_src   = (const int*)d_in[4];
    const int* pos_dst   = (const int*)d_in[5];
    const int* neg_src   = (const int*)d_in[6];
    const int* neg_dst   = (const int*)d_in[7];
    const float* W0      = (const float*)d_in[8];
    const float* b0      = (const float*)d_in[9];
    const float* W1      = (const float*)d_in[10];
    const float* b1      = (const float*)d_in[11];
    const float* W2      = (const float*)d_in[12];
    const float* b2      = (const float*)d_in[13];
    const float* P0      = (const float*)d_in[14];
    const float* pb0     = (const float*)d_in[15];
    const float* P1      = (const float*)d_in[16];
    const float* pb1     = (const float*)d_in[17];
    const float* P2      = (const float*)d_in[18];
    const float* pb2     = (const float*)d_in[19];
    float* out = (float*)d_out;

    float* ws = (float*)d_ws;
    float* norm_src = ws;                 // N
    float* norm_dst = ws + NN;            // N
    int* deg_out    = (int*)(ws + 2 * NN);
    int* deg_in     = (int*)(ws + 3 * NN);
    float* hw       = ws + 4 * NN;        // N*64
    float* agg      = ws + 4 * NN + 64 * NN;  // N*64

    // degrees + norms (graph static across layers)
    hipMemsetAsync(deg_out, 0, 2 * NN * sizeof(int), stream);
    deg_kernel<<<2048, 256, 0, stream>>>(src, dst, deg_out, deg_in, NE);
    norm_kernel<<<(NN + 255) / 256, 256, 0, stream>>>(deg_out, deg_in, norm_src, norm_dst, NN);

    // layer 0
    gemm_kernel<128, false><<<2048, 256, 0, stream>>>(x, W0, nullptr, norm_src, norm_dst, hw, NN);
    hipMemsetAsync(agg, 0, NN * 64 * sizeof(float), stream);
    scatter_kernel<<<4096, 256, 0, stream>>>(hw, ew + 0 * NE, src, dst, agg, NE);

    // layer 1 (finalize layer0: relu(agg*norm_dst+b0), scale, @W1)
    gemm_kernel<64, true><<<2048, 256, 0, stream>>>(agg, W1, b0, norm_src, norm_dst, hw, NN);
    hipMemsetAsync(agg, 0, NN * 64 * sizeof(float), stream);
    scatter_kernel<<<4096, 256, 0, stream>>>(hw, ew + 1 * NE, src, dst, agg, NE);

    // layer 2
    gemm_kernel<64, true><<<2048, 256, 0, stream>>>(agg, W2, b1, norm_src, norm_dst, hw, NN);
    hipMemsetAsync(agg, 0, NN * 64 * sizeof(float), stream);
    scatter_kernel<<<4096, 256, 0, stream>>>(hw, ew + 2 * NE, src, dst, agg, NE);

    // MLP over pos & neg pairs (finalizes layer 2 on the fly: agg*norm_dst + b2, no relu)
    mlp_kernel<<<2048, 256, 0, stream>>>(agg, norm_dst, b2, P0, pb0, P1, pb1, P2, pb2,
                                         pos_src, pos_dst, neg_src, neg_dst, out, NP);
}

// Round 2
// 764.359 us; speedup vs baseline: 2.5621x; 2.5621x over previous
//
#include <hip/hip_runtime.h>

// GCN link predictor, fp32 — round 2: CSR pull aggregation (no fp32 atomics),
// LDS-tiled GEMMs and MLP (no shuffle chains).
// N=100000, E=1e6 edges, P=1e5 pairs, IN=128, H=64.
//
// ws layout (float units):
//   0        norm_src   [N]
//   100000   norm_dst   [N]
//   200000   deg_out / cursor (int) [N]
//   300000   deg_in (int) [N]
//   400000   row_ptr (int) [N+1]
//   500004   csr_src (int) [E]
//   1500004  cew (float) [3*E]   (edge weights permuted into CSR order, 3 layers)
//   4500004  hw   [N*64]  (also reused as hfin after layer 2)
//   10900004 agg  [N*64]
// total 17300004 floats = 69.2 MB

#define NN 100000
#define NE 1000000
#define NP 100000

__global__ void deg_kernel(const int* __restrict__ src, const int* __restrict__ dst,
                           int* __restrict__ deg_out, int* __restrict__ deg_in, int E) {
    int tid = blockIdx.x * blockDim.x + threadIdx.x;
    int stride = gridDim.x * blockDim.x;
    for (int e = tid; e < E; e += stride) {
        atomicAdd(&deg_out[src[e]], 1);
        atomicAdd(&deg_in[dst[e]], 1);
    }
}

__global__ void norm_kernel(const int* __restrict__ deg_out, const int* __restrict__ deg_in,
                            float* __restrict__ norm_src, float* __restrict__ norm_dst, int n) {
    int i = blockIdx.x * blockDim.x + threadIdx.x;
    if (i < n) {
        norm_src[i] = rsqrtf(fmaxf((float)deg_out[i], 1.0f));
        norm_dst[i] = rsqrtf(fmaxf((float)deg_in[i], 1.0f));
    }
}

// single-block exclusive scan of deg[0..n) -> row_ptr[0..n], also copies into cursor.
__global__ __launch_bounds__(1024) void scan_kernel(const int* __restrict__ deg,
                                                    int* __restrict__ row_ptr,
                                                    int* __restrict__ cursor, int n) {
    __shared__ int sums[1024];
    const int tid = threadIdx.x;
    const int chunk = (n + 1023) >> 10;
    const int beg = tid * chunk;
    const int end = min(beg + chunk, n);
    int s = 0;
    for (int i = beg; i < end; ++i) s += deg[i];
    sums[tid] = s;
    __syncthreads();
    for (int off = 1; off < 1024; off <<= 1) {
        int v = (tid >= off) ? sums[tid - off] : 0;
        __syncthreads();
        sums[tid] += v;
        __syncthreads();
    }
    int run = (tid > 0) ? sums[tid - 1] : 0;  // exclusive prefix
    for (int i = beg; i < end; ++i) {
        row_ptr[i] = run;
        cursor[i] = run;
        run += deg[i];
    }
    if (tid == 1023) row_ptr[n] = run;
}

// place each edge into its dst row; permute all 3 layers' edge weights along.
__global__ void csr_fill(const int* __restrict__ src, const int* __restrict__ dst,
                         const float* __restrict__ ew, int* __restrict__ cursor,
                         int* __restrict__ csr_src, float* __restrict__ cew, int E) {
    int tid = blockIdx.x * blockDim.x + threadIdx.x;
    int stride = gridDim.x * blockDim.x;
    for (int e = tid; e < E; e += stride) {
        int d = dst[e];
        int slot = atomicAdd(&cursor[d], 1);
        csr_src[slot] = src[e];
        cew[slot] = ew[e];
        cew[E + slot] = ew[E + e];
        cew[2 * E + slot] = ew[2 * E + e];
    }
}

// 64-row LDS-tiled GEMM: out[row][j] = norm_src[row] * sum_k t[row][k]*W[k][j]
// PREV: t = relu(in*norm_dst + bias) (K=64)  else t = raw in (K=128, layer 0)
template <int K, bool PREV>
__global__ __launch_bounds__(256) void gemm_tile(const float* __restrict__ in,
                                                 const float* __restrict__ W,
                                                 const float* __restrict__ bias,
                                                 const float* __restrict__ norm_src,
                                                 const float* __restrict__ norm_dst,
                                                 float* __restrict__ out, int n) {
    __shared__ float Xs[64][K + 4];
    __shared__ float Ws[K * 64];
    __shared__ float bl[K];
    const int tid = threadIdx.x;
    for (int i = tid; i < K * 64; i += 256) Ws[i] = W[i];
    if (PREV && tid < K) bl[tid] = bias[tid];
    __syncthreads();

    const int ntiles = (n + 63) >> 6;
    const int tr = tid >> 4, tc = tid & 15;

    for (int tile = blockIdx.x; tile < ntiles; tile += gridDim.x) {
        // stage X tile (coalesced along k within each row)
        for (int idx = tid; idx < 64 * K; idx += 256) {
            int r = idx / K, k = idx % K;
            int row = tile * 64 + r;
            float v = 0.f;
            if (row < n) {
                v = in[row * K + k];
                if (PREV) v = fmaxf(v * norm_dst[row] + bl[k], 0.f);
            }
            Xs[r][k] = v;
        }
        __syncthreads();

        float acc[4][4] = {};
        for (int k = 0; k < K; ++k) {
            float4 w4 = *(const float4*)&Ws[k * 64 + tc * 4];
#pragma unroll
            for (int i = 0; i < 4; ++i) {
                float xv = Xs[tr * 4 + i][k];
                acc[i][0] = fmaf(xv, w4.x, acc[i][0]);
                acc[i][1] = fmaf(xv, w4.y, acc[i][1]);
                acc[i][2] = fmaf(xv, w4.z, acc[i][2]);
                acc[i][3] = fmaf(xv, w4.w, acc[i][3]);
            }
        }
#pragma unroll
        for (int i = 0; i < 4; ++i) {
            int row = tile * 64 + tr * 4 + i;
            if (row < n) {
                float ns = norm_src[row];
                float4 o = {acc[i][0] * ns, acc[i][1] * ns, acc[i][2] * ns, acc[i][3] * ns};
                *(float4*)&out[row * 64 + tc * 4] = o;
            }
        }
        __syncthreads();
    }
}

// CSR pull aggregation: one wave per dst node, register accumulation, no atomics.
__global__ __launch_bounds__(256) void aggregate(const float* __restrict__ hw,
                                                 const float* __restrict__ cew,
                                                 const int* __restrict__ csr_src,
                                                 const int* __restrict__ row_ptr,
                                                 float* __restrict__ agg, int n) {
    const int lane = threadIdx.x & 63;
    const int gw = (blockIdx.x * blockDim.x + threadIdx.x) >> 6;
    const int nw = (gridDim.x * blockDim.x) >> 6;
    for (int node = gw; node < n; node += nw) {
        int beg = row_ptr[node], end = row_ptr[node + 1];
        float a0 = 0.f, a1 = 0.f;
        int i = beg;
        for (; i + 1 < end; i += 2) {
            int s0 = csr_src[i], s1 = csr_src[i + 1];
            float w0 = cew[i], w1 = cew[i + 1];
            a0 = fmaf(hw[s0 * 64 + lane], w0, a0);
            a1 = fmaf(hw[s1 * 64 + lane], w1, a1);
        }
        if (i < end) a0 = fmaf(hw[csr_src[i] * 64 + lane], cew[i], a0);
        agg[node * 64 + lane] = a0 + a1;
    }
}

// hfin = agg*norm_dst + b2 (final conv layer output, no relu), float4-vectorized.
__global__ void hfin_kernel(const float* __restrict__ agg, const float* __restrict__ norm_dst,
                            const float* __restrict__ b2, float* __restrict__ hfin, int n) {
    int tid = blockIdx.x * blockDim.x + threadIdx.x;
    int stride = gridDim.x * blockDim.x;
    int total = n * 16;
    for (int idx = tid; idx < total; idx += stride) {
        int node = idx >> 4;
        int q = idx & 15;
        float nd = norm_dst[node];
        float4 a = ((const float4*)agg)[idx];
        float4 b = ((const float4*)b2)[q];
        float4 o = {fmaf(a.x, nd, b.x), fmaf(a.y, nd, b.y), fmaf(a.z, nd, b.z), fmaf(a.w, nd, b.w)};
        ((float4*)hfin)[idx] = o;
    }
}

// 64 pairs per tile: Z = h[a]*h[b] staged in LDS, 3-layer MLP as LDS-tiled GEMMs.
__global__ __launch_bounds__(256) void mlp_tile(const float* __restrict__ hfin,
                                                const float* __restrict__ P0,
                                                const float* __restrict__ pb0,
                                                const float* __restrict__ P1,
                                                const float* __restrict__ pb1,
                                                const float* __restrict__ P2,
                                                const float* __restrict__ pb2,
                                                const int* __restrict__ pos_src,
                                                const int* __restrict__ pos_dst,
                                                const int* __restrict__ neg_src,
                                                const int* __restrict__ neg_dst,
                                                float* __restrict__ out, int P) {
    __shared__ float Zs[64][68];
    __shared__ float W0s[64 * 64], W1s[64 * 64];
    __shared__ float pb0s[64], pb1s[64], P2s[64];
    __shared__ int pas[64], pbs[64];
    const int tid = threadIdx.x;
    for (int i = tid; i < 4096; i += 256) {
        W0s[i] = P0[i];
        W1s[i] = P1[i];
    }
    if (tid < 64) {
        pb0s[tid] = pb0[tid];
        pb1s[tid] = pb1[tid];
        P2s[tid] = P2[tid];
    }
    const float pb2v = pb2[0];
    const int lane = tid & 63, w = tid >> 6;
    const int tr = tid >> 4, tc = tid & 15;
    const int ntiles = (2 * P) >> 6;  // 3125, exact

    for (int tile = blockIdx.x; tile < ntiles; tile += gridDim.x) {
        const int base = tile << 6;
        __syncthreads();  // protect pas/Zs from previous iteration readers
        if (tid < 64) {
            int p = base + tid;
            pas[tid] = (p < P) ? pos_src[p] : neg_src[p - P];
            pbs[tid] = (p < P) ? pos_dst[p] : neg_dst[p - P];
        }
        __syncthreads();

        // gather + elementwise product into Zs
#pragma unroll 4
        for (int pi = w; pi < 64; pi += 4) {
            float ha = hfin[pas[pi] * 64 + lane];
            float hb = hfin[pbs[pi] * 64 + lane];
            Zs[pi][lane] = ha * hb;
        }
        __syncthreads();

        // layer 0: Z1 = relu(Z @ P0 + pb0)
        float acc[4][4];
#pragma unroll
        for (int i = 0; i < 4; ++i)
#pragma unroll
            for (int j = 0; j < 4; ++j) acc[i][j] = pb0s[tc * 4 + j];
        for (int k = 0; k < 64; ++k) {
            float4 w4 = *(const float4*)&W0s[k * 64 + tc * 4];
#pragma unroll
            for (int i = 0; i < 4; ++i) {
                float xv = Zs[tr * 4 + i][k];
                acc[i][0] = fmaf(xv, w4.x, acc[i][0]);
                acc[i][1] = fmaf(xv, w4.y, acc[i][1]);
                acc[i][2] = fmaf(xv, w4.z, acc[i][2]);
                acc[i][3] = fmaf(xv, w4.w, acc[i][3]);
            }
        }
        __syncthreads();
#pragma unroll
        for (int i = 0; i < 4; ++i)
#pragma unroll
            for (int j = 0; j < 4; ++j) Zs[tr * 4 + i][tc * 4 + j] = fmaxf(acc[i][j], 0.f);
        __syncthreads();

        // layer 1: Z2 = relu(Z1 @ P1 + pb1)
#pragma unroll
        for (int i = 0; i < 4; ++i)
#pragma unroll
            for (int j = 0; j < 4; ++j) acc[i][j] = pb1s[tc * 4 + j];
        for (int k = 0; k < 64; ++k) {
            float4 w4 = *(const float4*)&W1s[k * 64 + tc * 4];
#pragma unroll
            for (int i = 0; i < 4; ++i) {
                float xv = Zs[tr * 4 + i][k];
                acc[i][0] = fmaf(xv, w4.x, acc[i][0]);
                acc[i][1] = fmaf(xv, w4.y, acc[i][1]);
                acc[i][2] = fmaf(xv, w4.z, acc[i][2]);
                acc[i][3] = fmaf(xv, w4.w, acc[i][3]);
            }
        }
        __syncthreads();
#pragma unroll
        for (int i = 0; i < 4; ++i)
#pragma unroll
            for (int j = 0; j < 4; ++j) Zs[tr * 4 + i][tc * 4 + j] = fmaxf(acc[i][j], 0.f);
        __syncthreads();

        // final: out[p] = Z2[p] . P2 + pb2   (4 lanes per pair)
        {
            int p = tid >> 2, kq = tid & 3;
            float s = 0.f;
#pragma unroll
            for (int i = 0; i < 16; ++i) s = fmaf(Zs[p][kq * 16 + i], P2s[kq * 16 + i], s);
            s += __shfl_xor(s, 1, 64);
            s += __shfl_xor(s, 2, 64);
            if (kq == 0) out[base + p] = s + pb2v;
        }
    }
}

extern "C" void kernel_launch(void* const* d_in, const int* in_sizes, int n_in,
                              void* d_out, int out_size, void* d_ws, size_t ws_size,
                              hipStream_t stream) {
    const float* x     = (const float*)d_in[0];
    const float* ew    = (const float*)d_in[1];  // (3, E)
    const int* src     = (const int*)d_in[2];
    const int* dst     = (const int*)d_in[3];
    const int* pos_src = (const int*)d_in[4];
    const int* pos_dst = (const int*)d_in[5];
    const int* neg_src = (const int*)d_in[6];
    const int* neg_dst = (const int*)d_in[7];
    const float* W0    = (const float*)d_in[8];
    const float* b0    = (const float*)d_in[9];
    const float* W1    = (const float*)d_in[10];
    const float* b1    = (const float*)d_in[11];
    const float* W2    = (const float*)d_in[12];
    const float* b2    = (const float*)d_in[13];
    const float* P0    = (const float*)d_in[14];
    const float* pb0   = (const float*)d_in[15];
    const float* P1    = (const float*)d_in[16];
    const float* pb1   = (const float*)d_in[17];
    const float* P2    = (const float*)d_in[18];
    const float* pb2   = (const float*)d_in[19];
    float* out = (float*)d_out;

    float* ws = (float*)d_ws;
    float* norm_src = ws;                       // N
    float* norm_dst = ws + 100000;              // N
    int* cursor     = (int*)(ws + 200000);      // N (deg_out first, then cursor)
    int* deg_in     = (int*)(ws + 300000);      // N
    int* row_ptr    = (int*)(ws + 400000);      // N+1
    int* csr_src    = (int*)(ws + 500004);      // E
    float* cew      = ws + 1500004;             // 3E
    float* hw       = ws + 4500004;             // N*64 (reused as hfin)
    float* agg      = ws + 10900004;            // N*64

    // degrees + norms + CSR (rebuilt every call; graph static across layers)
    hipMemsetAsync(cursor, 0, 2 * NN * sizeof(int), stream);  // deg_out + deg_in
    deg_kernel<<<2048, 256, 0, stream>>>(src, dst, cursor, deg_in, NE);
    norm_kernel<<<(NN + 255) / 256, 256, 0, stream>>>(cursor, deg_in, norm_src, norm_dst, NN);
    scan_kernel<<<1, 1024, 0, stream>>>(deg_in, row_ptr, cursor, NN);
    csr_fill<<<2048, 256, 0, stream>>>(src, dst, ew, cursor, csr_src, cew, NE);

    // layer 0
    gemm_tile<128, false><<<1024, 256, 0, stream>>>(x, W0, nullptr, norm_src, norm_dst, hw, NN);
    aggregate<<<4096, 256, 0, stream>>>(hw, cew, csr_src, row_ptr, agg, NN);
    // layer 1 (finalizes layer 0 during staging: relu(agg*nd + b0))
    gemm_tile<64, true><<<1024, 256, 0, stream>>>(agg, W1, b0, norm_src, norm_dst, hw, NN);
    aggregate<<<4096, 256, 0, stream>>>(hw, cew + NE, csr_src, row_ptr, agg, NN);
    // layer 2
    gemm_tile<64, true><<<1024, 256, 0, stream>>>(agg, W2, b1, norm_src, norm_dst, hw, NN);
    aggregate<<<4096, 256, 0, stream>>>(hw, cew + 2 * NE, csr_src, row_ptr, agg, NN);

    // finalize h (no relu) into hfin (= hw buffer), then MLP over pairs
    hfin_kernel<<<2048, 256, 0, stream>>>(agg, norm_dst, b2, hw, NN);
    mlp_tile<<<1024, 256, 0, stream>>>(hw, P0, pb0, P1, pb1, P2, pb2,
                                       pos_src, pos_dst, neg_src, neg_dst, out, NP);
}

// Round 3
// 548.065 us; speedup vs baseline: 3.5733x; 1.3946x over previous
//
#include <hip/hip_runtime.h>

// GCN link predictor, fp32 — round 3: parallel 3-kernel device scan
// (round 2's single-block scan was 232us = 30% of runtime, latency-bound).
// N=100000, E=1e6 edges, P=1e5 pairs, IN=128, H=64.
//
// ws layout (float units):
//   0        norm_src   [N]
//   100000   norm_dst   [N]
//   200000   deg_out / cursor (int) [N]
//   300000   deg_in (int) [N]
//   400000   row_ptr (int) [N+1]
//   500004   csr_src (int) [E]
//   1500004  cew (float) [3*E]
//   4500004  hw   [N*64]  (scan scratch before layer 0; hfin after layer 2)
//   10900004 agg  [N*64]
// total 17300004 floats = 69.2 MB

#define NN 100000
#define NE 1000000
#define NP 100000
#define SCAN_NB 98  // ceil(100000/1024)

__global__ void deg_kernel(const int* __restrict__ src, const int* __restrict__ dst,
                           int* __restrict__ deg_out, int* __restrict__ deg_in, int E) {
    int tid = blockIdx.x * blockDim.x + threadIdx.x;
    int stride = gridDim.x * blockDim.x;
    for (int e = tid; e < E; e += stride) {
        atomicAdd(&deg_out[src[e]], 1);
        atomicAdd(&deg_in[dst[e]], 1);
    }
}

__global__ void norm_kernel(const int* __restrict__ deg_out, const int* __restrict__ deg_in,
                            float* __restrict__ norm_src, float* __restrict__ norm_dst, int n) {
    int i = blockIdx.x * blockDim.x + threadIdx.x;
    if (i < n) {
        norm_src[i] = rsqrtf(fmaxf((float)deg_out[i], 1.0f));
        norm_dst[i] = rsqrtf(fmaxf((float)deg_in[i], 1.0f));
    }
}

// --- 3-kernel scan: one element per thread, coalesced ---
__global__ __launch_bounds__(1024) void scan_block(const int* __restrict__ deg,
                                                   int* __restrict__ tmp_excl,
                                                   int* __restrict__ blocksums, int n) {
    __shared__ int wsums[16];
    const int i = blockIdx.x * 1024 + threadIdx.x;
    const int lane = threadIdx.x & 63, w = threadIdx.x >> 6;
    int v = (i < n) ? deg[i] : 0;
    int s = v;
#pragma unroll
    for (int off = 1; off < 64; off <<= 1) {
        int u = __shfl_up(s, off, 64);
        if (lane >= off) s += u;
    }
    if (lane == 63) wsums[w] = s;
    __syncthreads();
    if (w == 0) {
        int ws = (lane < 16) ? wsums[lane] : 0;
#pragma unroll
        for (int off = 1; off < 16; off <<= 1) {
            int u = __shfl_up(ws, off, 64);
            if (lane >= off) ws += u;
        }
        if (lane < 16) wsums[lane] = ws;  // inclusive scan of wave totals
    }
    __syncthreads();
    int excl = s - v + (w > 0 ? wsums[w - 1] : 0);
    if (i < n) tmp_excl[i] = excl;
    if (threadIdx.x == 1023) blocksums[blockIdx.x] = excl + v;  // block total
}

__global__ void scan_sums(int* __restrict__ bs, int nb) {
    __shared__ int wtot[2];
    const int t = threadIdx.x;  // 128 threads
    const int lane = t & 63, w = t >> 6;
    int v = (t < nb) ? bs[t] : 0;
    int s = v;
#pragma unroll
    for (int off = 1; off < 64; off <<= 1) {
        int u = __shfl_up(s, off, 64);
        if (lane >= off) s += u;
    }
    if (lane == 63) wtot[w] = s;
    __syncthreads();
    int excl = s - v + (w == 1 ? wtot[0] : 0);
    if (t < nb) bs[t] = excl;
}

__global__ __launch_bounds__(1024) void scan_apply(const int* __restrict__ tmp_excl,
                                                   const int* __restrict__ bs,
                                                   int* __restrict__ row_ptr,
                                                   int* __restrict__ cursor, int n) {
    const int i = blockIdx.x * 1024 + threadIdx.x;
    if (i < n) {
        int r = tmp_excl[i] + bs[blockIdx.x];
        row_ptr[i] = r;
        cursor[i] = r;
    }
    if (i == 0) row_ptr[n] = NE;  // all dst < N, so total is exactly E
}

// place each edge into its dst row; permute all 3 layers' edge weights along.
__global__ void csr_fill(const int* __restrict__ src, const int* __restrict__ dst,
                         const float* __restrict__ ew, int* __restrict__ cursor,
                         int* __restrict__ csr_src, float* __restrict__ cew, int E) {
    int tid = blockIdx.x * blockDim.x + threadIdx.x;
    int stride = gridDim.x * blockDim.x;
    for (int e = tid; e < E; e += stride) {
        int d = dst[e];
        int slot = atomicAdd(&cursor[d], 1);
        csr_src[slot] = src[e];
        cew[slot] = ew[e];
        cew[E + slot] = ew[E + e];
        cew[2 * E + slot] = ew[2 * E + e];
    }
}

// 64-row LDS-tiled GEMM: out[row][j] = norm_src[row] * sum_k t[row][k]*W[k][j]
// PREV: t = relu(in*norm_dst + bias) (K=64)  else t = raw in (K=128, layer 0)
template <int K, bool PREV>
__global__ __launch_bounds__(256) void gemm_tile(const float* __restrict__ in,
                                                 const float* __restrict__ W,
                                                 const float* __restrict__ bias,
                                                 const float* __restrict__ norm_src,
                                                 const float* __restrict__ norm_dst,
                                                 float* __restrict__ out, int n) {
    __shared__ float Xs[64][K + 4];
    __shared__ float Ws[K * 64];
    __shared__ float bl[K];
    const int tid = threadIdx.x;
    for (int i = tid; i < K * 64; i += 256) Ws[i] = W[i];
    if (PREV && tid < K) bl[tid] = bias[tid];
    __syncthreads();

    const int ntiles = (n + 63) >> 6;
    const int tr = tid >> 4, tc = tid & 15;

    for (int tile = blockIdx.x; tile < ntiles; tile += gridDim.x) {
        for (int idx = tid; idx < 64 * K; idx += 256) {
            int r = idx / K, k = idx % K;
            int row = tile * 64 + r;
            float v = 0.f;
            if (row < n) {
                v = in[row * K + k];
                if (PREV) v = fmaxf(v * norm_dst[row] + bl[k], 0.f);
            }
            Xs[r][k] = v;
        }
        __syncthreads();

        float acc[4][4] = {};
        for (int k = 0; k < K; ++k) {
            float4 w4 = *(const float4*)&Ws[k * 64 + tc * 4];
#pragma unroll
            for (int i = 0; i < 4; ++i) {
                float xv = Xs[tr * 4 + i][k];
                acc[i][0] = fmaf(xv, w4.x, acc[i][0]);
                acc[i][1] = fmaf(xv, w4.y, acc[i][1]);
                acc[i][2] = fmaf(xv, w4.z, acc[i][2]);
                acc[i][3] = fmaf(xv, w4.w, acc[i][3]);
            }
        }
#pragma unroll
        for (int i = 0; i < 4; ++i) {
            int row = tile * 64 + tr * 4 + i;
            if (row < n) {
                float ns = norm_src[row];
                float4 o = {acc[i][0] * ns, acc[i][1] * ns, acc[i][2] * ns, acc[i][3] * ns};
                *(float4*)&out[row * 64 + tc * 4] = o;
            }
        }
        __syncthreads();
    }
}

// CSR pull aggregation: one wave per dst node, register accumulation, no atomics.
__global__ __launch_bounds__(256) void aggregate(const float* __restrict__ hw,
                                                 const float* __restrict__ cew,
                                                 const int* __restrict__ csr_src,
                                                 const int* __restrict__ row_ptr,
                                                 float* __restrict__ agg, int n) {
    const int lane = threadIdx.x & 63;
    const int gw = (blockIdx.x * blockDim.x + threadIdx.x) >> 6;
    const int nw = (gridDim.x * blockDim.x) >> 6;
    for (int node = gw; node < n; node += nw) {
        int beg = row_ptr[node], end = row_ptr[node + 1];
        float a0 = 0.f, a1 = 0.f;
        int i = beg;
        for (; i + 1 < end; i += 2) {
            int s0 = csr_src[i], s1 = csr_src[i + 1];
            float w0 = cew[i], w1 = cew[i + 1];
            a0 = fmaf(hw[s0 * 64 + lane], w0, a0);
            a1 = fmaf(hw[s1 * 64 + lane], w1, a1);
        }
        if (i < end) a0 = fmaf(hw[csr_src[i] * 64 + lane], cew[i], a0);
        agg[node * 64 + lane] = a0 + a1;
    }
}

// hfin = agg*norm_dst + b2 (final conv layer output, no relu), float4-vectorized.
__global__ void hfin_kernel(const float* __restrict__ agg, const float* __restrict__ norm_dst,
                            const float* __restrict__ b2, float* __restrict__ hfin, int n) {
    int tid = blockIdx.x * blockDim.x + threadIdx.x;
    int stride = gridDim.x * blockDim.x;
    int total = n * 16;
    for (int idx = tid; idx < total; idx += stride) {
        int node = idx >> 4;
        int q = idx & 15;
        float nd = norm_dst[node];
        float4 a = ((const float4*)agg)[idx];
        float4 b = ((const float4*)b2)[q];
        float4 o = {fmaf(a.x, nd, b.x), fmaf(a.y, nd, b.y), fmaf(a.z, nd, b.z), fmaf(a.w, nd, b.w)};
        ((float4*)hfin)[idx] = o;
    }
}

// 64 pairs per tile: Z = h[a]*h[b] staged in LDS, 3-layer MLP as LDS-tiled GEMMs.
__global__ __launch_bounds__(256) void mlp_tile(const float* __restrict__ hfin,
                                                const float* __restrict__ P0,
                                                const float* __restrict__ pb0,
                                                const float* __restrict__ P1,
                                                const float* __restrict__ pb1,
                                                const float* __restrict__ P2,
                                                const float* __restrict__ pb2,
                                                const int* __restrict__ pos_src,
                                                const int* __restrict__ pos_dst,
                                                const int* __restrict__ neg_src,
                                                const int* __restrict__ neg_dst,
                                                float* __restrict__ out, int P) {
    __shared__ float Zs[64][68];
    __shared__ float W0s[64 * 64], W1s[64 * 64];
    __shared__ float pb0s[64], pb1s[64], P2s[64];
    __shared__ int pas[64], pbs[64];
    const int tid = threadIdx.x;
    for (int i = tid; i < 4096; i += 256) {
        W0s[i] = P0[i];
        W1s[i] = P1[i];
    }
    if (tid < 64) {
        pb0s[tid] = pb0[tid];
        pb1s[tid] = pb1[tid];
        P2s[tid] = P2[tid];
    }
    const float pb2v = pb2[0];
    const int lane = tid & 63, w = tid >> 6;
    const int tr = tid >> 4, tc = tid & 15;
    const int ntiles = (2 * P) >> 6;  // 3125, exact

    for (int tile = blockIdx.x; tile < ntiles; tile += gridDim.x) {
        const int base = tile << 6;
        __syncthreads();
        if (tid < 64) {
            int p = base + tid;
            pas[tid] = (p < P) ? pos_src[p] : neg_src[p - P];
            pbs[tid] = (p < P) ? pos_dst[p] : neg_dst[p - P];
        }
        __syncthreads();

#pragma unroll 4
        for (int pi = w; pi < 64; pi += 4) {
            float ha = hfin[pas[pi] * 64 + lane];
            float hb = hfin[pbs[pi] * 64 + lane];
            Zs[pi][lane] = ha * hb;
        }
        __syncthreads();

        float acc[4][4];
#pragma unroll
        for (int i = 0; i < 4; ++i)
#pragma unroll
            for (int j = 0; j < 4; ++j) acc[i][j] = pb0s[tc * 4 + j];
        for (int k = 0; k < 64; ++k) {
            float4 w4 = *(const float4*)&W0s[k * 64 + tc * 4];
#pragma unroll
            for (int i = 0; i < 4; ++i) {
                float xv = Zs[tr * 4 + i][k];
                acc[i][0] = fmaf(xv, w4.x, acc[i][0]);
                acc[i][1] = fmaf(xv, w4.y, acc[i][1]);
                acc[i][2] = fmaf(xv, w4.z, acc[i][2]);
                acc[i][3] = fmaf(xv, w4.w, acc[i][3]);
            }
        }
        __syncthreads();
#pragma unroll
        for (int i = 0; i < 4; ++i)
#pragma unroll
            for (int j = 0; j < 4; ++j) Zs[tr * 4 + i][tc * 4 + j] = fmaxf(acc[i][j], 0.f);
        __syncthreads();

#pragma unroll
        for (int i = 0; i < 4; ++i)
#pragma unroll
            for (int j = 0; j < 4; ++j) acc[i][j] = pb1s[tc * 4 + j];
        for (int k = 0; k < 64; ++k) {
            float4 w4 = *(const float4*)&W1s[k * 64 + tc * 4];
#pragma unroll
            for (int i = 0; i < 4; ++i) {
                float xv = Zs[tr * 4 + i][k];
                acc[i][0] = fmaf(xv, w4.x, acc[i][0]);
                acc[i][1] = fmaf(xv, w4.y, acc[i][1]);
                acc[i][2] = fmaf(xv, w4.z, acc[i][2]);
                acc[i][3] = fmaf(xv, w4.w, acc[i][3]);
            }
        }
        __syncthreads();
#pragma unroll
        for (int i = 0; i < 4; ++i)
#pragma unroll
            for (int j = 0; j < 4; ++j) Zs[tr * 4 + i][tc * 4 + j] = fmaxf(acc[i][j], 0.f);
        __syncthreads();

        {
            int p = tid >> 2, kq = tid & 3;
            float s = 0.f;
#pragma unroll
            for (int i = 0; i < 16; ++i) s = fmaf(Zs[p][kq * 16 + i], P2s[kq * 16 + i], s);
            s += __shfl_xor(s, 1, 64);
            s += __shfl_xor(s, 2, 64);
            if (kq == 0) out[base + p] = s + pb2v;
        }
    }
}

extern "C" void kernel_launch(void* const* d_in, const int* in_sizes, int n_in,
                              void* d_out, int out_size, void* d_ws, size_t ws_size,
                              hipStream_t stream) {
    const float* x     = (const float*)d_in[0];
    const float* ew    = (const float*)d_in[1];  // (3, E)
    const int* src     = (const int*)d_in[2];
    const int* dst     = (const int*)d_in[3];
    const int* pos_src = (const int*)d_in[4];
    const int* pos_dst = (const int*)d_in[5];
    const int* neg_src = (const int*)d_in[6];
    const int* neg_dst = (const int*)d_in[7];
    const float* W0    = (const float*)d_in[8];
    const float* b0    = (const float*)d_in[9];
    const float* W1    = (const float*)d_in[10];
    const float* b1    = (const float*)d_in[11];
    const float* W2    = (const float*)d_in[12];
    const float* b2    = (const float*)d_in[13];
    const float* P0    = (const float*)d_in[14];
    const float* pb0   = (const float*)d_in[15];
    const float* P1    = (const float*)d_in[16];
    const float* pb1   = (const float*)d_in[17];
    const float* P2    = (const float*)d_in[18];
    const float* pb2   = (const float*)d_in[19];
    float* out = (float*)d_out;

    float* ws = (float*)d_ws;
    float* norm_src = ws;                       // N
    float* norm_dst = ws + 100000;              // N
    int* cursor     = (int*)(ws + 200000);      // N (deg_out first, then cursor)
    int* deg_in     = (int*)(ws + 300000);      // N
    int* row_ptr    = (int*)(ws + 400000);      // N+1
    int* csr_src    = (int*)(ws + 500004);      // E
    float* cew      = ws + 1500004;             // 3E
    float* hw       = ws + 4500004;             // N*64 (scan scratch, then hw/hfin)
    float* agg      = ws + 10900004;            // N*64

    // scan scratch inside hw (not yet live)
    int* tmp_excl   = (int*)hw;                 // N
    int* blocksums  = (int*)hw + NN;            // SCAN_NB

    hipMemsetAsync(cursor, 0, 2 * NN * sizeof(int), stream);  // deg_out + deg_in
    deg_kernel<<<2048, 256, 0, stream>>>(src, dst, cursor, deg_in, NE);
    norm_kernel<<<(NN + 255) / 256, 256, 0, stream>>>(cursor, deg_in, norm_src, norm_dst, NN);
    scan_block<<<SCAN_NB, 1024, 0, stream>>>(deg_in, tmp_excl, blocksums, NN);
    scan_sums<<<1, 128, 0, stream>>>(blocksums, SCAN_NB);
    scan_apply<<<SCAN_NB, 1024, 0, stream>>>(tmp_excl, blocksums, row_ptr, cursor, NN);
    csr_fill<<<2048, 256, 0, stream>>>(src, dst, ew, cursor, csr_src, cew, NE);

    // layer 0
    gemm_tile<128, false><<<1024, 256, 0, stream>>>(x, W0, nullptr, norm_src, norm_dst, hw, NN);
    aggregate<<<4096, 256, 0, stream>>>(hw, cew, csr_src, row_ptr, agg, NN);
    // layer 1 (finalizes layer 0 during staging: relu(agg*nd + b0))
    gemm_tile<64, true><<<1024, 256, 0, stream>>>(agg, W1, b0, norm_src, norm_dst, hw, NN);
    aggregate<<<4096, 256, 0, stream>>>(hw, cew + NE, csr_src, row_ptr, agg, NN);
    // layer 2
    gemm_tile<64, true><<<1024, 256, 0, stream>>>(agg, W2, b1, norm_src, norm_dst, hw, NN);
    aggregate<<<4096, 256, 0, stream>>>(hw, cew + 2 * NE, csr_src, row_ptr, agg, NN);

    // finalize h (no relu) into hfin (= hw buffer), then MLP over pairs
    hfin_kernel<<<2048, 256, 0, stream>>>(agg, norm_dst, b2, hw, NN);
    mlp_tile<<<1024, 256, 0, stream>>>(hw, P0, pb0, P1, pb1, P2, pb2,
                                       pos_src, pos_dst, neg_src, neg_dst, out, NP);
}

// Round 5
// 522.677 us; speedup vs baseline: 3.7468x; 1.0486x over previous
//
#include <hip/hip_runtime.h>

// GCN link predictor, fp32 — round 5 (= round 4 plan, macro-capture bug fixed):
//  * csr_fill packs (src,w0,w1,w2) into one float4 scattered write
//  * aggregate consumes packed edge struct + fuses next-layer input transform
//  * gemm/mlp inner loops k4-vectorized (float4 LDS reads)
//
// ws layout (float units):
//   0        norm_src [N]
//   100000   norm_dst [N]
//   200000   deg_out / cursor (int) [N]
//   300000   deg_in (int) [N]
//   400000   row_ptr (int) [N+1]
//   500004   cedge (float4) [E]          (src, w_l0, w_l1, w_l2) per edge
//   4500004  hw   [N*64]   (scan scratch before layer 0)
//   10900004 agg  [N*64]
// total 17300004 floats = 69.2 MB

#define NN 100000
#define NE 1000000
#define NP 100000
#define SCAN_NB 98

__device__ __forceinline__ void row_fma(float4& acc, float xv, const float4& wv) {
    acc.x = fmaf(xv, wv.x, acc.x);
    acc.y = fmaf(xv, wv.y, acc.y);
    acc.z = fmaf(xv, wv.z, acc.z);
    acc.w = fmaf(xv, wv.w, acc.w);
}

__global__ void deg_kernel(const int* __restrict__ src, const int* __restrict__ dst,
                           int* __restrict__ deg_out, int* __restrict__ deg_in, int E) {
    int tid = blockIdx.x * blockDim.x + threadIdx.x;
    int stride = gridDim.x * blockDim.x;
    for (int e = tid; e < E; e += stride) {
        atomicAdd(&deg_out[src[e]], 1);
        atomicAdd(&deg_in[dst[e]], 1);
    }
}

__global__ void norm_kernel(const int* __restrict__ deg_out, const int* __restrict__ deg_in,
                            float* __restrict__ norm_src, float* __restrict__ norm_dst, int n) {
    int i = blockIdx.x * blockDim.x + threadIdx.x;
    if (i < n) {
        norm_src[i] = rsqrtf(fmaxf((float)deg_out[i], 1.0f));
        norm_dst[i] = rsqrtf(fmaxf((float)deg_in[i], 1.0f));
    }
}

__global__ __launch_bounds__(1024) void scan_block(const int* __restrict__ deg,
                                                   int* __restrict__ tmp_excl,
                                                   int* __restrict__ blocksums, int n) {
    __shared__ int wsums[16];
    const int i = blockIdx.x * 1024 + threadIdx.x;
    const int lane = threadIdx.x & 63, w = threadIdx.x >> 6;
    int v = (i < n) ? deg[i] : 0;
    int s = v;
#pragma unroll
    for (int off = 1; off < 64; off <<= 1) {
        int u = __shfl_up(s, off, 64);
        if (lane >= off) s += u;
    }
    if (lane == 63) wsums[w] = s;
    __syncthreads();
    if (w == 0) {
        int wv = (lane < 16) ? wsums[lane] : 0;
#pragma unroll
        for (int off = 1; off < 16; off <<= 1) {
            int u = __shfl_up(wv, off, 64);
            if (lane >= off) wv += u;
        }
        if (lane < 16) wsums[lane] = wv;
    }
    __syncthreads();
    int excl = s - v + (w > 0 ? wsums[w - 1] : 0);
    if (i < n) tmp_excl[i] = excl;
    if (threadIdx.x == 1023) blocksums[blockIdx.x] = excl + v;
}

__global__ void scan_sums(int* __restrict__ bs, int nb) {
    __shared__ int wtot[2];
    const int t = threadIdx.x;  // 128 threads
    const int lane = t & 63, w = t >> 6;
    int v = (t < nb) ? bs[t] : 0;
    int s = v;
#pragma unroll
    for (int off = 1; off < 64; off <<= 1) {
        int u = __shfl_up(s, off, 64);
        if (lane >= off) s += u;
    }
    if (lane == 63) wtot[w] = s;
    __syncthreads();
    int excl = s - v + (w == 1 ? wtot[0] : 0);
    if (t < nb) bs[t] = excl;
}

__global__ __launch_bounds__(1024) void scan_apply(const int* __restrict__ tmp_excl,
                                                   const int* __restrict__ bs,
                                                   int* __restrict__ row_ptr,
                                                   int* __restrict__ cursor, int n) {
    const int i = blockIdx.x * 1024 + threadIdx.x;
    if (i < n) {
        int r = tmp_excl[i] + bs[blockIdx.x];
        row_ptr[i] = r;
        cursor[i] = r;
    }
    if (i == 0) row_ptr[n] = NE;
}

// pack each edge into its dst row: one scattered 16B write per edge.
__global__ void csr_fill(const int* __restrict__ src, const int* __restrict__ dst,
                         const float* __restrict__ ew, int* __restrict__ cursor,
                         float4* __restrict__ cedge, int E) {
    int tid = blockIdx.x * blockDim.x + threadIdx.x;
    int stride = gridDim.x * blockDim.x;
    for (int e = tid; e < E; e += stride) {
        int d = dst[e];
        int slot = atomicAdd(&cursor[d], 1);
        float4 c;
        c.x = __int_as_float(src[e]);
        c.y = ew[e];
        c.z = ew[NE + e];
        c.w = ew[2 * NE + e];
        cedge[slot] = c;
    }
}

// CSR pull aggregation, one wave per dst node. Fused epilogue:
//  FINAL=0: out = relu(a*norm_dst + bias)*norm_src   (input for next pure GEMM)
//  FINAL=1: out = a*norm_dst + bias                  (b2; final conv output, no relu)
template <int WSEL, bool FINAL>
__global__ __launch_bounds__(256) void aggregate(const float* __restrict__ hw,
                                                 const float4* __restrict__ cedge,
                                                 const int* __restrict__ row_ptr,
                                                 const float* __restrict__ norm_src,
                                                 const float* __restrict__ norm_dst,
                                                 const float* __restrict__ bias,
                                                 float* __restrict__ outx, int n) {
    const int lane = threadIdx.x & 63;
    const int gw = (blockIdx.x * blockDim.x + threadIdx.x) >> 6;
    const int nw = (gridDim.x * blockDim.x) >> 6;
    const float blane = bias[lane];
    for (int node = gw; node < n; node += nw) {
        int beg = row_ptr[node], end = row_ptr[node + 1];
        float a0 = 0.f, a1 = 0.f;
        int i = beg;
        for (; i + 1 < end; i += 2) {
            float4 c0 = cedge[i], c1 = cedge[i + 1];
            int s0 = __float_as_int(c0.x), s1 = __float_as_int(c1.x);
            float w0 = (WSEL == 0) ? c0.y : (WSEL == 1) ? c0.z : c0.w;
            float w1 = (WSEL == 0) ? c1.y : (WSEL == 1) ? c1.z : c1.w;
            a0 = fmaf(hw[s0 * 64 + lane], w0, a0);
            a1 = fmaf(hw[s1 * 64 + lane], w1, a1);
        }
        if (i < end) {
            float4 c0 = cedge[i];
            int s0 = __float_as_int(c0.x);
            float w0 = (WSEL == 0) ? c0.y : (WSEL == 1) ? c0.z : c0.w;
            a0 = fmaf(hw[s0 * 64 + lane], w0, a0);
        }
        float a = a0 + a1;
        float nd = norm_dst[node];
        float t;
        if (FINAL) {
            t = fmaf(a, nd, blane);
        } else {
            t = fmaxf(fmaf(a, nd, blane), 0.f) * norm_src[node];
        }
        outx[node * 64 + lane] = t;
    }
}

// pure 64-row GEMM tile: out[row][j] = (SCALE ? norm_src[row] : 1) * sum_k in[row][k]*W[k][j]
template <int K, bool SCALE>
__global__ __launch_bounds__(256) void gemm_tile(const float* __restrict__ in,
                                                 const float* __restrict__ W,
                                                 const float* __restrict__ norm_src,
                                                 float* __restrict__ out, int n) {
    __shared__ float Xs[64][K + 4];
    __shared__ float Ws[K * 64];
    const int tid = threadIdx.x;
    for (int i = tid; i < K * 16; i += 256) ((float4*)Ws)[i] = ((const float4*)W)[i];
    __syncthreads();

    const int ntiles = (n + 63) >> 6;
    const int tr = tid >> 4, tc = tid & 15;

    for (int tile = blockIdx.x; tile < ntiles; tile += gridDim.x) {
        for (int idx = tid; idx < K * 16; idx += 256) {
            int r = idx / (K / 4), kq = idx % (K / 4);
            int row = tile * 64 + r;
            float4 v = make_float4(0.f, 0.f, 0.f, 0.f);
            if (row < n) v = *(const float4*)&in[row * K + kq * 4];
            *(float4*)&Xs[r][kq * 4] = v;
        }
        __syncthreads();

        float4 acc0 = {0, 0, 0, 0}, acc1 = {0, 0, 0, 0}, acc2 = {0, 0, 0, 0}, acc3 = {0, 0, 0, 0};
#pragma unroll 4
        for (int k4 = 0; k4 < K / 4; ++k4) {
            const int kb = k4 * 4;
            float4 xv0 = *(const float4*)&Xs[tr * 4 + 0][kb];
            float4 xv1 = *(const float4*)&Xs[tr * 4 + 1][kb];
            float4 xv2 = *(const float4*)&Xs[tr * 4 + 2][kb];
            float4 xv3 = *(const float4*)&Xs[tr * 4 + 3][kb];
            const float* wb = &Ws[kb * 64 + tc * 4];
            float4 wk;
            wk = *(const float4*)(wb);
            row_fma(acc0, xv0.x, wk); row_fma(acc1, xv1.x, wk); row_fma(acc2, xv2.x, wk); row_fma(acc3, xv3.x, wk);
            wk = *(const float4*)(wb + 64);
            row_fma(acc0, xv0.y, wk); row_fma(acc1, xv1.y, wk); row_fma(acc2, xv2.y, wk); row_fma(acc3, xv3.y, wk);
            wk = *(const float4*)(wb + 128);
            row_fma(acc0, xv0.z, wk); row_fma(acc1, xv1.z, wk); row_fma(acc2, xv2.z, wk); row_fma(acc3, xv3.z, wk);
            wk = *(const float4*)(wb + 192);
            row_fma(acc0, xv0.w, wk); row_fma(acc1, xv1.w, wk); row_fma(acc2, xv2.w, wk); row_fma(acc3, xv3.w, wk);
        }

#pragma unroll
        for (int i = 0; i < 4; ++i) {
            int row = tile * 64 + tr * 4 + i;
            if (row < n) {
                float4 o = (i == 0) ? acc0 : (i == 1) ? acc1 : (i == 2) ? acc2 : acc3;
                if (SCALE) {
                    float ns = norm_src[row];
                    o.x *= ns; o.y *= ns; o.z *= ns; o.w *= ns;
                }
                *(float4*)&out[row * 64 + tc * 4] = o;
            }
        }
        __syncthreads();
    }
}

#define ZST 76  // Zs row stride

// 64 pairs/tile MLP, k4-vectorized.
__global__ __launch_bounds__(256) void mlp_tile(const float* __restrict__ hfin,
                                                const float* __restrict__ P0,
                                                const float* __restrict__ pb0,
                                                const float* __restrict__ P1,
                                                const float* __restrict__ pb1,
                                                const float* __restrict__ P2,
                                                const float* __restrict__ pb2,
                                                const int* __restrict__ pos_src,
                                                const int* __restrict__ pos_dst,
                                                const int* __restrict__ neg_src,
                                                const int* __restrict__ neg_dst,
                                                float* __restrict__ out, int P) {
    __shared__ float Zs[64][ZST];
    __shared__ float W0s[4096], W1s[4096];
    __shared__ float pb0s[64], pb1s[64], P2s[64];
    __shared__ int pas[64], pbs[64];
    const int tid = threadIdx.x;
    for (int i = tid; i < 1024; i += 256) {
        ((float4*)W0s)[i] = ((const float4*)P0)[i];
        ((float4*)W1s)[i] = ((const float4*)P1)[i];
    }
    if (tid < 64) {
        pb0s[tid] = pb0[tid];
        pb1s[tid] = pb1[tid];
        P2s[tid] = P2[tid];
    }
    const float pb2v = pb2[0];
    const int lane = tid & 63, w = tid >> 6;
    const int tr = tid >> 4, tc = tid & 15;
    const int ntiles = (2 * P) >> 6;  // 3125

    for (int tile = blockIdx.x; tile < ntiles; tile += gridDim.x) {
        const int base = tile << 6;
        __syncthreads();
        if (tid < 64) {
            int p = base + tid;
            pas[tid] = (p < P) ? pos_src[p] : neg_src[p - P];
            pbs[tid] = (p < P) ? pos_dst[p] : neg_dst[p - P];
        }
        __syncthreads();

#pragma unroll 4
        for (int pi = w; pi < 64; pi += 4) {
            float ha = hfin[pas[pi] * 64 + lane];
            float hb = hfin[pbs[pi] * 64 + lane];
            Zs[pi][lane] = ha * hb;
        }
        __syncthreads();

        // layer 0
        float4 acc0, acc1, acc2, acc3;
        {
            float4 binit = *(const float4*)&pb0s[tc * 4];
            acc0 = binit; acc1 = binit; acc2 = binit; acc3 = binit;
        }
#pragma unroll 4
        for (int k4 = 0; k4 < 16; ++k4) {
            const int kb = k4 * 4;
            float4 xv0 = *(const float4*)&Zs[tr * 4 + 0][kb];
            float4 xv1 = *(const float4*)&Zs[tr * 4 + 1][kb];
            float4 xv2 = *(const float4*)&Zs[tr * 4 + 2][kb];
            float4 xv3 = *(const float4*)&Zs[tr * 4 + 3][kb];
            const float* wb = &W0s[kb * 64 + tc * 4];
            float4 wk;
            wk = *(const float4*)(wb);
            row_fma(acc0, xv0.x, wk); row_fma(acc1, xv1.x, wk); row_fma(acc2, xv2.x, wk); row_fma(acc3, xv3.x, wk);
            wk = *(const float4*)(wb + 64);
            row_fma(acc0, xv0.y, wk); row_fma(acc1, xv1.y, wk); row_fma(acc2, xv2.y, wk); row_fma(acc3, xv3.y, wk);
            wk = *(const float4*)(wb + 128);
            row_fma(acc0, xv0.z, wk); row_fma(acc1, xv1.z, wk); row_fma(acc2, xv2.z, wk); row_fma(acc3, xv3.z, wk);
            wk = *(const float4*)(wb + 192);
            row_fma(acc0, xv0.w, wk); row_fma(acc1, xv1.w, wk); row_fma(acc2, xv2.w, wk); row_fma(acc3, xv3.w, wk);
        }
        __syncthreads();
#pragma unroll
        for (int i = 0; i < 4; ++i) {
            float4 o = (i == 0) ? acc0 : (i == 1) ? acc1 : (i == 2) ? acc2 : acc3;
            o.x = fmaxf(o.x, 0.f); o.y = fmaxf(o.y, 0.f); o.z = fmaxf(o.z, 0.f); o.w = fmaxf(o.w, 0.f);
            *(float4*)&Zs[tr * 4 + i][tc * 4] = o;
        }
        __syncthreads();

        // layer 1
        {
            float4 binit = *(const float4*)&pb1s[tc * 4];
            acc0 = binit; acc1 = binit; acc2 = binit; acc3 = binit;
        }
#pragma unroll 4
        for (int k4 = 0; k4 < 16; ++k4) {
            const int kb = k4 * 4;
            float4 xv0 = *(const float4*)&Zs[tr * 4 + 0][kb];
            float4 xv1 = *(const float4*)&Zs[tr * 4 + 1][kb];
            float4 xv2 = *(const float4*)&Zs[tr * 4 + 2][kb];
            float4 xv3 = *(const float4*)&Zs[tr * 4 + 3][kb];
            const float* wb = &W1s[kb * 64 + tc * 4];
            float4 wk;
            wk = *(const float4*)(wb);
            row_fma(acc0, xv0.x, wk); row_fma(acc1, xv1.x, wk); row_fma(acc2, xv2.x, wk); row_fma(acc3, xv3.x, wk);
            wk = *(const float4*)(wb + 64);
            row_fma(acc0, xv0.y, wk); row_fma(acc1, xv1.y, wk); row_fma(acc2, xv2.y, wk); row_fma(acc3, xv3.y, wk);
            wk = *(const float4*)(wb + 128);
            row_fma(acc0, xv0.z, wk); row_fma(acc1, xv1.z, wk); row_fma(acc2, xv2.z, wk); row_fma(acc3, xv3.z, wk);
            wk = *(const float4*)(wb + 192);
            row_fma(acc0, xv0.w, wk); row_fma(acc1, xv1.w, wk); row_fma(acc2, xv2.w, wk); row_fma(acc3, xv3.w, wk);
        }
        __syncthreads();
#pragma unroll
        for (int i = 0; i < 4; ++i) {
            float4 o = (i == 0) ? acc0 : (i == 1) ? acc1 : (i == 2) ? acc2 : acc3;
            o.x = fmaxf(o.x, 0.f); o.y = fmaxf(o.y, 0.f); o.z = fmaxf(o.z, 0.f); o.w = fmaxf(o.w, 0.f);
            *(float4*)&Zs[tr * 4 + i][tc * 4] = o;
        }
        __syncthreads();

        // final GEMV: out[p] = Z2[p] . P2 + pb2
        {
            int p = tid >> 2, kq = tid & 3;
            float s = 0.f;
#pragma unroll
            for (int i = 0; i < 16; ++i) s = fmaf(Zs[p][kq * 16 + i], P2s[kq * 16 + i], s);
            s += __shfl_xor(s, 1, 64);
            s += __shfl_xor(s, 2, 64);
            if (kq == 0) out[base + p] = s + pb2v;
        }
    }
}

extern "C" void kernel_launch(void* const* d_in, const int* in_sizes, int n_in,
                              void* d_out, int out_size, void* d_ws, size_t ws_size,
                              hipStream_t stream) {
    const float* x     = (const float*)d_in[0];
    const float* ew    = (const float*)d_in[1];  // (3, E)
    const int* src     = (const int*)d_in[2];
    const int* dst     = (const int*)d_in[3];
    const int* pos_src = (const int*)d_in[4];
    const int* pos_dst = (const int*)d_in[5];
    const int* neg_src = (const int*)d_in[6];
    const int* neg_dst = (const int*)d_in[7];
    const float* W0    = (const float*)d_in[8];
    const float* b0    = (const float*)d_in[9];
    const float* W1    = (const float*)d_in[10];
    const float* b1    = (const float*)d_in[11];
    const float* W2    = (const float*)d_in[12];
    const float* b2    = (const float*)d_in[13];
    const float* P0    = (const float*)d_in[14];
    const float* pb0   = (const float*)d_in[15];
    const float* P1    = (const float*)d_in[16];
    const float* pb1   = (const float*)d_in[17];
    const float* P2    = (const float*)d_in[18];
    const float* pb2   = (const float*)d_in[19];
    float* out = (float*)d_out;

    float* ws = (float*)d_ws;
    float* norm_src = ws;                     // N
    float* norm_dst = ws + 100000;            // N
    int* cursor     = (int*)(ws + 200000);    // N
    int* deg_in     = (int*)(ws + 300000);    // N
    int* row_ptr    = (int*)(ws + 400000);    // N+1
    float4* cedge   = (float4*)(ws + 500004); // E
    float* hw       = ws + 4500004;           // N*64
    float* agg      = ws + 10900004;          // N*64

    int* tmp_excl  = (int*)hw;       // scan scratch (hw not yet live)
    int* blocksums = (int*)hw + NN;

    hipMemsetAsync(cursor, 0, 2 * NN * sizeof(int), stream);  // deg_out + deg_in
    deg_kernel<<<2048, 256, 0, stream>>>(src, dst, cursor, deg_in, NE);
    norm_kernel<<<(NN + 255) / 256, 256, 0, stream>>>(cursor, deg_in, norm_src, norm_dst, NN);
    scan_block<<<SCAN_NB, 1024, 0, stream>>>(deg_in, tmp_excl, blocksums, NN);
    scan_sums<<<1, 128, 0, stream>>>(blocksums, SCAN_NB);
    scan_apply<<<SCAN_NB, 1024, 0, stream>>>(tmp_excl, blocksums, row_ptr, cursor, NN);
    csr_fill<<<2048, 256, 0, stream>>>(src, dst, ew, cursor, cedge, NE);

    const int NT = (NN + 63) / 64;  // 1563 tiles

    // layer 0: hw = (x @ W0) * ns   (agg epilogue produces relu(a*nd+b0)*ns)
    gemm_tile<128, true><<<NT, 256, 0, stream>>>(x, W0, norm_src, hw, NN);
    aggregate<0, false><<<4096, 256, 0, stream>>>(hw, cedge, row_ptr, norm_src, norm_dst, b0, agg, NN);
    // layer 1
    gemm_tile<64, false><<<NT, 256, 0, stream>>>(agg, W1, nullptr, hw, NN);
    aggregate<1, false><<<4096, 256, 0, stream>>>(hw, cedge, row_ptr, norm_src, norm_dst, b1, agg, NN);
    // layer 2 (final: agg <- a*nd + b2, no relu — this IS hfin)
    gemm_tile<64, false><<<NT, 256, 0, stream>>>(agg, W2, nullptr, hw, NN);
    aggregate<2, true><<<4096, 256, 0, stream>>>(hw, cedge, row_ptr, norm_src, norm_dst, b2, agg, NN);

    // MLP over pos & neg pairs
    mlp_tile<<<1024, 256, 0, stream>>>(agg, P0, pb0, P1, pb1, P2, pb2,
                                       pos_src, pos_dst, neg_src, neg_dst, out, NP);
}